// Round 10
// baseline (144.843 us; speedup 1.0000x reference)
//
#include <hip/hip_runtime.h>

#define N_NODES 100000
#define N_EDGES 1600000
#define IN_DIM 256
#define OUT_DIM 32

#define SB_SHIFT 8                          // super-bucket = node >> 8 (256 nodes)
#define NSB ((N_NODES + 255) >> 8)          // 391
#define SBCAP 4480                          // mean 4092 + ~6 sigma
#define EBLK 2048                           // edges per part1 block (R10: halved)
#define NB1 ((N_EDGES + EBLK - 1) / EBLK)   // 782

typedef __attribute__((ext_vector_type(8))) short short8;
typedef __attribute__((ext_vector_type(16))) float f32x16;

#define WT_STRIDE 264    // 256 + 8 pad (bf16 elems)

__device__ inline unsigned short f2bf(float f) {
    unsigned u = __float_as_uint(f);
    unsigned r = u + 0x7FFF + ((u >> 16) & 1);   // round-to-nearest-even
    return (unsigned short)(r >> 16);
}

// ---------------------------------------------------------------------------
// k_part1: dual partition (dst-side u32 payloads, src-side u8 payloads).
// Window claims for BOTH sides packed into ONE 64-bit atomicAdd per
// (block,bucket): lo 32 = dst count, hi 32 = src count.
// ---------------------------------------------------------------------------
__global__ __launch_bounds__(512) void k_part1(const int* __restrict__ src,
                                               const int* __restrict__ dst,
                                               unsigned long long* __restrict__ qcnt,
                                               unsigned* __restrict__ gsb,
                                               unsigned char* __restrict__ gss) {
    __shared__ int hist[NSB], bbase[NSB], cur[NSB];
    __shared__ int hist_s[NSB], bbase_s[NSB], cur_s[NSB];
    const int tid = threadIdx.x;
    const int e0 = blockIdx.x * EBLK;
    const int eend = min(e0 + EBLK, N_EDGES);

    for (int i = tid; i < NSB; i += 512) {
        hist[i] = 0; cur[i] = 0; hist_s[i] = 0; cur_s[i] = 0;
    }
    __syncthreads();

    // pass A: both histograms (LDS atomics only; 4 iters/thread)
    for (int e = e0 + tid; e < eend; e += 512) {
        atomicAdd(&hist[dst[e] >> SB_SHIFT], 1);
        atomicAdd(&hist_s[src[e] >> SB_SHIFT], 1);
    }
    __syncthreads();

    // packed claim: one u64 atomic covers both sides
    for (int i = tid; i < NSB; i += 512) {
        unsigned long long pack =
            ((unsigned long long)(unsigned)hist_s[i] << 32) | (unsigned)hist[i];
        unsigned long long old = atomicAdd(&qcnt[i], pack);
        bbase[i]   = (int)(old & 0xFFFFFFFFull);   // dst window base
        bbase_s[i] = (int)(old >> 32);             // src window base
    }
    __syncthreads();

    // pass B: re-read (L3-hot) and scatter into private windows
    for (int e = e0 + tid; e < eend; e += 512) {
        int d = dst[e];
        int s = src[e];
        int r = d >> SB_SHIFT;
        int lp = atomicAdd(&cur[r], 1);
        int pos = bbase[r] + lp;
        if (pos < SBCAP)
            gsb[(size_t)r * SBCAP + pos] = ((unsigned)(d & 255) << 17) | (unsigned)s;
        int rs = s >> SB_SHIFT;
        int lp2 = atomicAdd(&cur_s[rs], 1);
        int pos2 = bbase_s[rs] + lp2;
        if (pos2 < SBCAP)
            gss[(size_t)rs * SBCAP + pos2] = (unsigned char)(s & 255);
    }
}

// ---------------------------------------------------------------------------
// k_combo (R10): per super-bucket r —
//   (1) src-side u8 histogram -> deg_out   (was k_deg2)
//   (2) redundant LDS scan of dst counts -> this bucket's esrc base (was k_scanb)
//   (3) exact counting sort -> esrc, row_ptr, deg_in   (was k_part2)
// qcnt int-view: qcnt2[2i] = dst count, qcnt2[2i+1] = src count.
// ---------------------------------------------------------------------------
__global__ __launch_bounds__(512) void k_combo(const int* __restrict__ qcnt2,
                                               const unsigned* __restrict__ gsb,
                                               const unsigned char* __restrict__ gss,
                                               int* __restrict__ deg_out,
                                               int* __restrict__ row_ptr,
                                               int* __restrict__ deg_in,
                                               int* __restrict__ esrc) {
    __shared__ int h8[256];
    __shared__ int sc[512];
    __shared__ int hist[256];
    __shared__ int pref[256];
    __shared__ int cur[256];

    const int r = blockIdx.x;
    const int tid = threadIdx.x;

    if (tid < 256) { h8[tid] = 0; hist[tid] = 0; cur[tid] = 0; }
    __syncthreads();

    // ---- (1) deg_out histogram over src-side bucket r
    int cnt_s = qcnt2[2 * r + 1];
    if (cnt_s > SBCAP) cnt_s = SBCAP;
    const unsigned char* sp = gss + (size_t)r * SBCAP;
    for (int i = tid; i < cnt_s; i += 512)
        atomicAdd(&h8[sp[i]], 1);

    // ---- (2) exclusive scan of all dst counts (redundant per block, cheap)
    int v = (tid < NSB) ? min(qcnt2[2 * tid], SBCAP) : 0;
    sc[tid] = v;
    __syncthreads();
    #pragma unroll
    for (int off = 1; off < 512; off <<= 1) {
        int t = (tid >= off) ? sc[tid - off] : 0;
        __syncthreads();
        sc[tid] += t;
        __syncthreads();
    }
    const int cnt = min(qcnt2[2 * r], SBCAP);
    const int base = sc[r] - cnt;          // exclusive prefix at r

    // write deg_out (h8 complete since the first scan barrier)
    {
        int n = (r << SB_SHIFT) + tid;
        if (tid < 256 && n < N_NODES) deg_out[n] = h8[tid];
    }

    // ---- (3) counting sort of dst-side bucket r
    const unsigned* bp = gsb + (size_t)r * SBCAP;

    for (int i = tid; i < cnt; i += 512)
        atomicAdd(&hist[bp[i] >> 17], 1);
    __syncthreads();

    int hv = 0;
    if (tid < 256) { hv = hist[tid]; pref[tid] = hv; }
    __syncthreads();
    #pragma unroll
    for (int off = 1; off < 256; off <<= 1) {
        int t = (tid < 256 && tid >= off) ? pref[tid - off] : 0;
        __syncthreads();
        if (tid < 256) pref[tid] += t;
        __syncthreads();
    }

    if (tid < 256) {
        int excl = pref[tid] - hv;
        int n = (r << SB_SHIFT) + tid;
        if (n < N_NODES) {
            row_ptr[n] = base + excl;
            deg_in[n] = hv;
        }
        pref[tid] = excl;
    }
    __syncthreads();

    for (int i = tid; i < cnt; i += 512) {
        unsigned pay = bp[i];
        int l = (int)(pay >> 17);
        int lp = atomicAdd(&cur[l], 1);
        esrc[base + pref[l] + lp] = (int)(pay & 0x1FFFF);
    }
}

// ---------------------------------------------------------------------------
// k_gemm (MFMA bf16): h = (x @ W) * norm_src. Layouts HW-verified in R8.
// ---------------------------------------------------------------------------
__global__ __launch_bounds__(256) void k_gemm(const float* __restrict__ x,
                                              const float* __restrict__ W,
                                              const int* __restrict__ deg_out,
                                              float* __restrict__ h) {
    __shared__ unsigned short WT[32 * WT_STRIDE];   // 16896 B

    const int tid = threadIdx.x;
    #pragma unroll
    for (int i = 0; i < 32; ++i) {
        int idx = tid + i * 256;            // k = idx>>5, c = idx&31
        WT[(idx & 31) * WT_STRIDE + (idx >> 5)] = f2bf(W[idx]);
    }
    __syncthreads();

    const int wv = tid >> 6;
    const int lane = tid & 63;
    const int col = lane & 31;
    const int hi = lane >> 5;

    const int row0 = blockIdx.x * 128 + wv * 32;
    int grow = row0 + col;
    int growc = grow < N_NODES ? grow : N_NODES - 1;
    const float4* xrow = reinterpret_cast<const float4*>(x + (size_t)growc * IN_DIM);

    f32x16 acc = {0.f,0.f,0.f,0.f,0.f,0.f,0.f,0.f,
                  0.f,0.f,0.f,0.f,0.f,0.f,0.f,0.f};

    #pragma unroll 4
    for (int t = 0; t < 16; ++t) {
        int k4 = t * 4 + hi * 2;            // k = t*16 + hi*8
        float4 p0 = xrow[k4];
        float4 p1 = xrow[k4 + 1];
        short8 a;
        a[0] = (short)f2bf(p0.x); a[1] = (short)f2bf(p0.y);
        a[2] = (short)f2bf(p0.z); a[3] = (short)f2bf(p0.w);
        a[4] = (short)f2bf(p1.x); a[5] = (short)f2bf(p1.y);
        a[6] = (short)f2bf(p1.z); a[7] = (short)f2bf(p1.w);
        short8 bfr = *reinterpret_cast<const short8*>(
            &WT[col * WT_STRIDE + t * 16 + hi * 8]);
        acc = __builtin_amdgcn_mfma_f32_32x32x16_bf16(a, bfr, acc, 0, 0, 0);
    }

    int dg = deg_out[growc];
    float nrm = rsqrtf((float)(dg > 1 ? dg : 1));

    #pragma unroll
    for (int r = 0; r < 16; ++r) {
        int rowi = (r & 3) + 8 * (r >> 2) + 4 * hi;
        float nr = __shfl(nrm, rowi, 64);
        int go = row0 + rowi;
        if (go < N_NODES)
            h[(size_t)go * OUT_DIM + col] = acc[r] * nr;
    }
}

// ---------------------------------------------------------------------------
// k_gather: wave per node, 8 edges/round, shfl_xor reduce, fused norm+bias
// ---------------------------------------------------------------------------
__global__ __launch_bounds__(256) void k_gather(const int* __restrict__ esrc,
                                                const int* __restrict__ row_ptr,
                                                const int* __restrict__ deg_in,
                                                const float* __restrict__ h,
                                                const float* __restrict__ bias,
                                                float* __restrict__ out) {
    int node = (blockIdx.x * 256 + threadIdx.x) >> 6;
    if (node >= N_NODES) return;
    int lane = threadIdx.x & 63;
    int j0 = lane >> 3;   // edge slot 0..7
    int q  = lane & 7;    // col quad 0..7

    int start = row_ptr[node];
    int deg = deg_in[node];

    float4 acc = make_float4(0.f, 0.f, 0.f, 0.f);
    int rounds = (deg + 7) >> 3;
    for (int rr = 0; rr < rounds; ++rr) {
        int j = rr * 8 + j0;
        if (j < deg) {
            int s = esrc[start + j];
            float4 hv = *reinterpret_cast<const float4*>(&h[(size_t)s * OUT_DIM + q * 4]);
            acc.x += hv.x; acc.y += hv.y; acc.z += hv.z; acc.w += hv.w;
        }
    }
    #pragma unroll
    for (int m = 8; m <= 32; m <<= 1) {
        acc.x += __shfl_xor(acc.x, m);
        acc.y += __shfl_xor(acc.y, m);
        acc.z += __shfl_xor(acc.z, m);
        acc.w += __shfl_xor(acc.w, m);
    }
    if (j0 == 0) {
        float nrm = rsqrtf((float)(deg > 1 ? deg : 1));
        float4 bb = *reinterpret_cast<const float4*>(&bias[q * 4]);
        float4 o = make_float4(acc.x * nrm + bb.x, acc.y * nrm + bb.y,
                               acc.z * nrm + bb.z, acc.w * nrm + bb.w);
        *reinterpret_cast<float4*>(&out[(size_t)node * OUT_DIM + q * 4]) = o;
    }
}

// ---------------------------------------------------------------------------
extern "C" void kernel_launch(void* const* d_in, const int* in_sizes, int n_in,
                              void* d_out, int out_size, void* d_ws, size_t ws_size,
                              hipStream_t stream) {
    const float* x   = (const float*)d_in[0];
    const int*   src = (const int*)d_in[1];
    const int*   dst = (const int*)d_in[2];
    const float* W   = (const float*)d_in[3];
    const float* b   = (const float*)d_in[4];
    float* out = (float*)d_out;

    // ws: qcnt u64[NSB] | deg_out[N] row_ptr[N] deg_in[N] pad ->
    //     h f32[N*32] | gsb u32[NSB*SBCAP] | esrc i32[E] | gss u8[NSB*SBCAP]
    unsigned long long* qcnt = (unsigned long long*)d_ws;
    int* qcnt2   = (int*)d_ws;                   // int view of qcnt
    int* deg_out = (int*)(qcnt + NSB);
    int* row_ptr = deg_out + N_NODES;
    int* deg_in  = row_ptr + N_NODES;
    int* pad     = deg_in + N_NODES;             // 782 + 300000 = 300782 ints
    float* h     = (float*)(pad + 2);            // 300784 ints -> 16B aligned
    unsigned* gsb = (unsigned*)(h + (size_t)N_NODES * OUT_DIM);
    int* esrc    = (int*)(gsb + (size_t)NSB * SBCAP);
    unsigned char* gss = (unsigned char*)(esrc + N_EDGES);

    hipMemsetAsync(qcnt, 0, NSB * sizeof(unsigned long long), stream);

    k_part1<<<NB1, 512, 0, stream>>>(src, dst, qcnt, gsb, gss);

    k_combo<<<NSB, 512, 0, stream>>>(qcnt2, gsb, gss, deg_out, row_ptr, deg_in, esrc);

    k_gemm<<<(N_NODES + 127) / 128, 256, 0, stream>>>(x, W, deg_out, h);

    k_gather<<<(N_NODES * 64 + 255) / 256, 256, 0, stream>>>(esrc, row_ptr, deg_in, h, b, out);
}

// Round 11
// 126.998 us; speedup vs baseline: 1.1405x; 1.1405x over previous
//
#include <hip/hip_runtime.h>

#define N_NODES 100000
#define N_EDGES 1600000
#define IN_DIM 256
#define OUT_DIM 32

#define SB_SHIFT 8                          // super-bucket = node >> 8 (256 nodes)
#define NSB ((N_NODES + 255) >> 8)          // 391
#define SBCAP 4480                          // mean 4092 + ~6 sigma
#define EBLK 2048                           // edges per part1 block
#define NB1 ((N_EDGES + EBLK - 1) / EBLK)   // 782

typedef __attribute__((ext_vector_type(8))) short short8;
typedef __attribute__((ext_vector_type(16))) float f32x16;

#define WT_STRIDE 264    // 256 + 8 pad (bf16 elems)

__device__ inline unsigned short f2bf(float f) {
    unsigned u = __float_as_uint(f);
    unsigned r = u + 0x7FFF + ((u >> 16) & 1);   // round-to-nearest-even
    return (unsigned short)(r >> 16);
}

// ---------------------------------------------------------------------------
// k_part1 (R11: single global pass). Edges staged in LDS during histogram
// pass; scatter pass reads LDS. Dual partition: dst-side u32 payloads,
// src-side u8 payloads. Packed u64 window claims.
// ---------------------------------------------------------------------------
__global__ __launch_bounds__(512) void k_part1(const int* __restrict__ src,
                                               const int* __restrict__ dst,
                                               unsigned long long* __restrict__ qcnt,
                                               unsigned* __restrict__ gsb,
                                               unsigned char* __restrict__ gss) {
    __shared__ int hist[NSB], bbase[NSB], cur[NSB];
    __shared__ int hist_s[NSB], bbase_s[NSB], cur_s[NSB];
    __shared__ int es[EBLK], ed[EBLK];               // 16 KB staging
    const int tid = threadIdx.x;
    const int e0 = blockIdx.x * EBLK;
    const int n = min(EBLK, N_EDGES - e0);

    for (int i = tid; i < NSB; i += 512) {
        hist[i] = 0; cur[i] = 0; hist_s[i] = 0; cur_s[i] = 0;
    }
    __syncthreads();

    // pass A: load once, stage in LDS, histogram both sides
    for (int i = tid; i < n; i += 512) {
        int s = src[e0 + i];
        int d = dst[e0 + i];
        es[i] = s; ed[i] = d;
        atomicAdd(&hist[d >> SB_SHIFT], 1);
        atomicAdd(&hist_s[s >> SB_SHIFT], 1);
    }
    __syncthreads();

    // packed claim: one u64 atomic covers both sides (lo=dst, hi=src)
    for (int i = tid; i < NSB; i += 512) {
        unsigned long long pack =
            ((unsigned long long)(unsigned)hist_s[i] << 32) | (unsigned)hist[i];
        unsigned long long old = atomicAdd(&qcnt[i], pack);
        bbase[i]   = (int)(old & 0xFFFFFFFFull);
        bbase_s[i] = (int)(old >> 32);
    }
    __syncthreads();

    // pass B: scatter from LDS into private global windows
    for (int i = tid; i < n; i += 512) {
        int d = ed[i];
        int s = es[i];
        int r = d >> SB_SHIFT;
        int lp = atomicAdd(&cur[r], 1);
        int pos = bbase[r] + lp;
        if (pos < SBCAP)
            gsb[(size_t)r * SBCAP + pos] = ((unsigned)(d & 255) << 17) | (unsigned)s;
        int rs = s >> SB_SHIFT;
        int lp2 = atomicAdd(&cur_s[rs], 1);
        int pos2 = bbase_s[rs] + lp2;
        if (pos2 < SBCAP)
            gss[(size_t)rs * SBCAP + pos2] = (unsigned char)(s & 255);
    }
}

// ---------------------------------------------------------------------------
// k_deg2: per-super-bucket u8 histogram -> deg_out (coalesced write)
// ---------------------------------------------------------------------------
__global__ __launch_bounds__(256) void k_deg2(const int* __restrict__ qcnt2,
                                              const unsigned char* __restrict__ gss,
                                              int* __restrict__ deg_out) {
    __shared__ int hist[256];
    const int r = blockIdx.x;
    const int tid = threadIdx.x;
    hist[tid] = 0;
    __syncthreads();
    int cnt = qcnt2[2 * r + 1];
    if (cnt > SBCAP) cnt = SBCAP;
    const unsigned char* bp = gss + (size_t)r * SBCAP;
    for (int i = tid; i < cnt; i += 256)
        atomicAdd(&hist[bp[i]], 1);
    __syncthreads();
    int nn = (r << SB_SHIFT) + tid;
    if (nn < N_NODES) deg_out[nn] = hist[tid];
}

// ---------------------------------------------------------------------------
// k_gemm (MFMA bf16): h = (x @ W) * norm_src. Layouts HW-verified in R8.
// ---------------------------------------------------------------------------
__global__ __launch_bounds__(256) void k_gemm(const float* __restrict__ x,
                                              const float* __restrict__ W,
                                              const int* __restrict__ deg_out,
                                              float* __restrict__ h) {
    __shared__ unsigned short WT[32 * WT_STRIDE];   // 16896 B

    const int tid = threadIdx.x;
    #pragma unroll
    for (int i = 0; i < 32; ++i) {
        int idx = tid + i * 256;            // k = idx>>5, c = idx&31
        WT[(idx & 31) * WT_STRIDE + (idx >> 5)] = f2bf(W[idx]);
    }
    __syncthreads();

    const int wv = tid >> 6;
    const int lane = tid & 63;
    const int col = lane & 31;
    const int hi = lane >> 5;

    const int row0 = blockIdx.x * 128 + wv * 32;
    int grow = row0 + col;
    int growc = grow < N_NODES ? grow : N_NODES - 1;
    const float4* xrow = reinterpret_cast<const float4*>(x + (size_t)growc * IN_DIM);

    f32x16 acc = {0.f,0.f,0.f,0.f,0.f,0.f,0.f,0.f,
                  0.f,0.f,0.f,0.f,0.f,0.f,0.f,0.f};

    #pragma unroll 4
    for (int t = 0; t < 16; ++t) {
        int k4 = t * 4 + hi * 2;            // k = t*16 + hi*8
        float4 p0 = xrow[k4];
        float4 p1 = xrow[k4 + 1];
        short8 a;
        a[0] = (short)f2bf(p0.x); a[1] = (short)f2bf(p0.y);
        a[2] = (short)f2bf(p0.z); a[3] = (short)f2bf(p0.w);
        a[4] = (short)f2bf(p1.x); a[5] = (short)f2bf(p1.y);
        a[6] = (short)f2bf(p1.z); a[7] = (short)f2bf(p1.w);
        short8 bfr = *reinterpret_cast<const short8*>(
            &WT[col * WT_STRIDE + t * 16 + hi * 8]);
        acc = __builtin_amdgcn_mfma_f32_32x32x16_bf16(a, bfr, acc, 0, 0, 0);
    }

    int dg = deg_out[growc];
    float nrm = rsqrtf((float)(dg > 1 ? dg : 1));

    #pragma unroll
    for (int r = 0; r < 16; ++r) {
        int rowi = (r & 3) + 8 * (r >> 2) + 4 * hi;
        float nr = __shfl(nrm, rowi, 64);
        int go = row0 + rowi;
        if (go < N_NODES)
            h[(size_t)go * OUT_DIM + col] = acc[r] * nr;
    }
}

// ---------------------------------------------------------------------------
// k_combo2 (R11): per super-bucket — stage payloads in LDS, counting-sort
// into LDS esl, then gather h directly and write out. No global esrc /
// row_ptr / deg_in, no global scan.
// Gather: 8 threads per node (thread = col quad), 64 nodes per sweep,
// 4-edge unroll with independent loads for ILP.
// ---------------------------------------------------------------------------
__global__ __launch_bounds__(512) void k_combo2(const int* __restrict__ qcnt2,
                                                const unsigned* __restrict__ gsb,
                                                const float* __restrict__ h,
                                                const float* __restrict__ bias,
                                                float* __restrict__ out) {
    __shared__ unsigned pstage[SBCAP];   // 17920 B
    __shared__ int esl[SBCAP];           // 17920 B
    __shared__ int hist[256];
    __shared__ int pref[256];
    __shared__ int cur[256];

    const int r = blockIdx.x;
    const int tid = threadIdx.x;

    if (tid < 256) { hist[tid] = 0; cur[tid] = 0; }
    int cnt = qcnt2[2 * r];
    if (cnt > SBCAP) cnt = SBCAP;
    const unsigned* bp = gsb + (size_t)r * SBCAP;
    __syncthreads();

    // stage + histogram (single global read of the bucket)
    for (int i = tid; i < cnt; i += 512) {
        unsigned pay = bp[i];
        pstage[i] = pay;
        atomicAdd(&hist[pay >> 17], 1);
    }
    __syncthreads();

    // exclusive scan of hist -> pref
    int v = 0;
    if (tid < 256) { v = hist[tid]; pref[tid] = v; }
    __syncthreads();
    #pragma unroll
    for (int off = 1; off < 256; off <<= 1) {
        int t = (tid < 256 && tid >= off) ? pref[tid - off] : 0;
        __syncthreads();
        if (tid < 256) pref[tid] += t;
        __syncthreads();
    }
    if (tid < 256) pref[tid] -= v;   // exclusive start per local node
    __syncthreads();

    // counting sort into LDS
    for (int i = tid; i < cnt; i += 512) {
        unsigned pay = pstage[i];
        int l = (int)(pay >> 17);
        int lp = atomicAdd(&cur[l], 1);
        esl[pref[l] + lp] = (int)(pay & 0x1FFFF);
    }
    __syncthreads();

    // fused gather + finalize
    const int q = tid & 7;            // col quad
    const int nl = tid >> 3;          // node slot 0..63
    const float4* h4 = reinterpret_cast<const float4*>(h);
    const float4 bb = reinterpret_cast<const float4*>(bias)[q];
    #pragma unroll
    for (int sweep = 0; sweep < 4; ++sweep) {
        int l = sweep * 64 + nl;
        int st = pref[l];
        int deg = hist[l];
        float4 acc = make_float4(0.f, 0.f, 0.f, 0.f);
        int j = 0;
        for (; j + 4 <= deg; j += 4) {
            int s0 = esl[st + j + 0];
            int s1 = esl[st + j + 1];
            int s2 = esl[st + j + 2];
            int s3 = esl[st + j + 3];
            float4 a0 = h4[s0 * 8 + q];
            float4 a1 = h4[s1 * 8 + q];
            float4 a2 = h4[s2 * 8 + q];
            float4 a3 = h4[s3 * 8 + q];
            acc.x += (a0.x + a1.x) + (a2.x + a3.x);
            acc.y += (a0.y + a1.y) + (a2.y + a3.y);
            acc.z += (a0.z + a1.z) + (a2.z + a3.z);
            acc.w += (a0.w + a1.w) + (a2.w + a3.w);
        }
        for (; j < deg; ++j) {
            int s = esl[st + j];
            float4 a = h4[s * 8 + q];
            acc.x += a.x; acc.y += a.y; acc.z += a.z; acc.w += a.w;
        }
        int node = (r << SB_SHIFT) + l;
        if (node < N_NODES) {
            float nrm = rsqrtf((float)(deg > 1 ? deg : 1));
            float4 o = make_float4(acc.x * nrm + bb.x, acc.y * nrm + bb.y,
                                   acc.z * nrm + bb.z, acc.w * nrm + bb.w);
            reinterpret_cast<float4*>(out)[(size_t)node * 8 + q] = o;
        }
    }
}

// ---------------------------------------------------------------------------
extern "C" void kernel_launch(void* const* d_in, const int* in_sizes, int n_in,
                              void* d_out, int out_size, void* d_ws, size_t ws_size,
                              hipStream_t stream) {
    const float* x   = (const float*)d_in[0];
    const int*   src = (const int*)d_in[1];
    const int*   dst = (const int*)d_in[2];
    const float* W   = (const float*)d_in[3];
    const float* b   = (const float*)d_in[4];
    float* out = (float*)d_out;

    // ws: deg_out int[N] | qcnt u64[NSB] | pad 8B | h f32[N*32] |
    //     gsb u32[NSB*SBCAP] | gss u8[NSB*SBCAP]
    int* deg_out = (int*)d_ws;                                    // 400000 B
    unsigned long long* qcnt = (unsigned long long*)(deg_out + N_NODES);
    int* qcnt2   = (int*)qcnt;
    float* h     = (float*)((char*)qcnt + NSB * 8 + 8);           // 403136 B, 16-aligned
    unsigned* gsb = (unsigned*)(h + (size_t)N_NODES * OUT_DIM);
    unsigned char* gss = (unsigned char*)(gsb + (size_t)NSB * SBCAP);

    hipMemsetAsync(qcnt, 0, NSB * sizeof(unsigned long long), stream);

    k_part1<<<NB1, 512, 0, stream>>>(src, dst, qcnt, gsb, gss);

    k_deg2<<<NSB, 256, 0, stream>>>(qcnt2, gss, deg_out);

    k_gemm<<<(N_NODES + 127) / 128, 256, 0, stream>>>(x, W, deg_out, h);

    k_combo2<<<NSB, 512, 0, stream>>>(qcnt2, gsb, h, b, out);
}

// Round 12
// 114.849 us; speedup vs baseline: 1.2612x; 1.1058x over previous
//
#include <hip/hip_runtime.h>

#define N_NODES 100000
#define N_EDGES 1600000
#define IN_DIM 256
#define OUT_DIM 32

#define SB_SHIFT 8                          // super-bucket = node >> 8 (256 nodes)
#define NSB ((N_NODES + 255) >> 8)          // 391
#define SBCAP 4480                          // mean 4092 + ~6 sigma
#define EBLK 2048                           // edges per part1 block
#define NB1 ((N_EDGES + EBLK - 1) / EBLK)   // 782
#define NGB ((N_NODES + 255) / 256)         // 391 gemm blocks (256 rows each)
#define HCAP 2368                           // half-bucket capacity (mean 2048 + 7 sigma)

typedef __attribute__((ext_vector_type(8))) short short8;
typedef __attribute__((ext_vector_type(16))) float f32x16;

#define WT_STRIDE 264    // 256 + 8 pad (bf16 elems)

__device__ inline unsigned short f2bf(float f) {
    unsigned u = __float_as_uint(f);
    unsigned r = u + 0x7FFF + ((u >> 16) & 1);   // round-to-nearest-even
    return (unsigned short)(r >> 16);
}

// ---------------------------------------------------------------------------
// K1 mega-kernel: 1173 blocks. bid%3==0 -> gemm_raw block (391 of them),
// else -> part1 block (782). Interleaved so both kinds co-reside per CU:
// part1 is latency-bound, gemm is MFMA/BW-bound -> they overlap.
// Shared LDS region aliased per branch (branch is block-uniform).
// ---------------------------------------------------------------------------
__global__ __launch_bounds__(512) void k_mega(const int* __restrict__ src,
                                              const int* __restrict__ dst,
                                              unsigned long long* __restrict__ qcnt,
                                              unsigned* __restrict__ gsb,
                                              unsigned char* __restrict__ gss,
                                              const float* __restrict__ x,
                                              const float* __restrict__ W,
                                              float* __restrict__ h_raw) {
    __shared__ __align__(16) int smemI[6444];   // 25776 B, max of both branches
    const int tid = threadIdx.x;
    const int bid = blockIdx.x;
    const int g = bid / 3;
    const int rem = bid - g * 3;

    if (rem == 0) {
        // ---------------- GEMM branch: rows [g*256, g*256+256), 8 waves ----
        unsigned short* WT = (unsigned short*)smemI;   // 32*264*2 = 16896 B
        #pragma unroll
        for (int i = 0; i < 16; ++i) {
            int idx = tid + i * 512;        // k = idx>>5, c = idx&31
            WT[(idx & 31) * WT_STRIDE + (idx >> 5)] = f2bf(W[idx]);
        }
        __syncthreads();

        const int wv = tid >> 6;            // 0..7
        const int lane = tid & 63;
        const int col = lane & 31;
        const int hi = lane >> 5;

        const int row0 = g * 256 + wv * 32;
        int grow = row0 + col;
        int growc = grow < N_NODES ? grow : N_NODES - 1;
        const float4* xrow = reinterpret_cast<const float4*>(x + (size_t)growc * IN_DIM);

        f32x16 acc = {0.f,0.f,0.f,0.f,0.f,0.f,0.f,0.f,
                      0.f,0.f,0.f,0.f,0.f,0.f,0.f,0.f};

        #pragma unroll 4
        for (int t = 0; t < 16; ++t) {
            int k4 = t * 4 + hi * 2;        // k = t*16 + hi*8
            float4 p0 = xrow[k4];
            float4 p1 = xrow[k4 + 1];
            short8 a;
            a[0] = (short)f2bf(p0.x); a[1] = (short)f2bf(p0.y);
            a[2] = (short)f2bf(p0.z); a[3] = (short)f2bf(p0.w);
            a[4] = (short)f2bf(p1.x); a[5] = (short)f2bf(p1.y);
            a[6] = (short)f2bf(p1.z); a[7] = (short)f2bf(p1.w);
            short8 bfr = *reinterpret_cast<const short8*>(
                &WT[col * WT_STRIDE + t * 16 + hi * 8]);
            acc = __builtin_amdgcn_mfma_f32_32x32x16_bf16(a, bfr, acc, 0, 0, 0);
        }

        #pragma unroll
        for (int r = 0; r < 16; ++r) {
            int rowi = (r & 3) + 8 * (r >> 2) + 4 * hi;
            int go = row0 + rowi;
            if (go < N_NODES)
                h_raw[(size_t)go * OUT_DIM + col] = acc[r];   // norm deferred
        }
    } else {
        // ---------------- part1 branch (R11 single-pass dual partition) ----
        const int pb = 2 * g + rem - 1;     // 0..781
        int* hist    = smemI;               // NSB
        int* bbase   = smemI + NSB;
        int* cur     = smemI + 2 * NSB;
        int* hist_s  = smemI + 3 * NSB;
        int* bbase_s = smemI + 4 * NSB;
        int* cur_s   = smemI + 5 * NSB;
        int* es      = smemI + 6 * NSB;           // EBLK
        int* ed      = smemI + 6 * NSB + EBLK;    // EBLK  (ends at 6442)

        const int e0 = pb * EBLK;
        const int n = min(EBLK, N_EDGES - e0);

        for (int i = tid; i < NSB; i += 512) {
            hist[i] = 0; cur[i] = 0; hist_s[i] = 0; cur_s[i] = 0;
        }
        __syncthreads();

        for (int i = tid; i < n; i += 512) {
            int s = src[e0 + i];
            int d = dst[e0 + i];
            es[i] = s; ed[i] = d;
            atomicAdd(&hist[d >> SB_SHIFT], 1);
            atomicAdd(&hist_s[s >> SB_SHIFT], 1);
        }
        __syncthreads();

        for (int i = tid; i < NSB; i += 512) {
            unsigned long long pack =
                ((unsigned long long)(unsigned)hist_s[i] << 32) | (unsigned)hist[i];
            unsigned long long old = atomicAdd(&qcnt[i], pack);
            bbase[i]   = (int)(old & 0xFFFFFFFFull);
            bbase_s[i] = (int)(old >> 32);
        }
        __syncthreads();

        for (int i = tid; i < n; i += 512) {
            int d = ed[i];
            int s = es[i];
            int r = d >> SB_SHIFT;
            int lp = atomicAdd(&cur[r], 1);
            int pos = bbase[r] + lp;
            if (pos < SBCAP)
                gsb[(size_t)r * SBCAP + pos] = ((unsigned)(d & 255) << 17) | (unsigned)s;
            int rs = s >> SB_SHIFT;
            int lp2 = atomicAdd(&cur_s[rs], 1);
            int pos2 = bbase_s[rs] + lp2;
            if (pos2 < SBCAP)
                gss[(size_t)rs * SBCAP + pos2] = (unsigned char)(s & 255);
        }
    }
}

// ---------------------------------------------------------------------------
// K2: per-super-bucket u8 histogram -> nrm_src table (coalesced write)
// ---------------------------------------------------------------------------
__global__ __launch_bounds__(256) void k_deg2(const int* __restrict__ qcnt2,
                                              const unsigned char* __restrict__ gss,
                                              float* __restrict__ nrmtab) {
    __shared__ int hist[256];
    const int r = blockIdx.x;
    const int tid = threadIdx.x;
    hist[tid] = 0;
    __syncthreads();
    int cnt = qcnt2[2 * r + 1];
    if (cnt > SBCAP) cnt = SBCAP;
    const unsigned char* bp = gss + (size_t)r * SBCAP;
    for (int i = tid; i < cnt; i += 256)
        atomicAdd(&hist[bp[i]], 1);
    __syncthreads();
    int nn = (r << SB_SHIFT) + tid;
    if (nn < N_NODES) {
        int dg = hist[tid];
        nrmtab[nn] = rsqrtf((float)(dg > 1 ? dg : 1));
    }
}

// ---------------------------------------------------------------------------
// K3: half-bucket sort+gather. 782 blocks; block = (bucket r, half).
// Filter-compact own half's payloads into LDS, counting-sort over 128 bins,
// gather h_raw[s]*nrm[s], finalize with nrm_dst + bias.
// ---------------------------------------------------------------------------
__global__ __launch_bounds__(512) void k_combo2(const int* __restrict__ qcnt2,
                                                const unsigned* __restrict__ gsb,
                                                const float* __restrict__ h,
                                                const float* __restrict__ nrmtab,
                                                const float* __restrict__ bias,
                                                float* __restrict__ out) {
    __shared__ unsigned pstage[HCAP];    // 9472 B
    __shared__ int esl[HCAP];            // 9472 B
    __shared__ int hist[128];
    __shared__ int pref[128];
    __shared__ int cur[128];
    __shared__ int scnt;

    const int r = blockIdx.x >> 1;
    const int half = blockIdx.x & 1;
    const int tid = threadIdx.x;

    if (tid < 128) { hist[tid] = 0; cur[tid] = 0; }
    if (tid == 0) scnt = 0;
    int cnt = qcnt2[2 * r];
    if (cnt > SBCAP) cnt = SBCAP;
    const unsigned* bp = gsb + (size_t)r * SBCAP;
    __syncthreads();

    // stage: filter-compact own half, histogram 128 local bins
    for (int i = tid; i < cnt; i += 512) {
        unsigned pay = bp[i];
        int l = (int)(pay >> 17);
        if ((l >> 7) == half) {
            int idx = atomicAdd(&scnt, 1);
            if (idx < HCAP) {
                pstage[idx] = pay;
                atomicAdd(&hist[l & 127], 1);
            }
        }
    }
    __syncthreads();
    int mycnt = scnt < HCAP ? scnt : HCAP;

    // exclusive scan of hist[128]
    int v = 0;
    if (tid < 128) { v = hist[tid]; pref[tid] = v; }
    __syncthreads();
    #pragma unroll
    for (int off = 1; off < 128; off <<= 1) {
        int t = (tid < 128 && tid >= off) ? pref[tid - off] : 0;
        __syncthreads();
        if (tid < 128) pref[tid] += t;
        __syncthreads();
    }
    if (tid < 128) pref[tid] -= v;
    __syncthreads();

    // counting sort into LDS
    for (int i = tid; i < mycnt; i += 512) {
        unsigned pay = pstage[i];
        int l = (int)(pay >> 17) & 127;
        int lp = atomicAdd(&cur[l], 1);
        esl[pref[l] + lp] = (int)(pay & 0x1FFFF);
    }
    __syncthreads();

    // gather + finalize: 8 threads/node, 2 sweeps of 64 node slots
    const int q = tid & 7;
    const int nl = tid >> 3;
    const float4* h4 = reinterpret_cast<const float4*>(h);
    const float4 bb = reinterpret_cast<const float4*>(bias)[q];
    #pragma unroll
    for (int sweep = 0; sweep < 2; ++sweep) {
        int l = sweep * 64 + nl;          // 0..127
        int st = pref[l];
        int deg = hist[l];
        float4 acc = make_float4(0.f, 0.f, 0.f, 0.f);
        int j = 0;
        for (; j + 4 <= deg; j += 4) {
            int s0 = esl[st + j + 0];
            int s1 = esl[st + j + 1];
            int s2 = esl[st + j + 2];
            int s3 = esl[st + j + 3];
            float w0 = nrmtab[s0];
            float w1 = nrmtab[s1];
            float w2 = nrmtab[s2];
            float w3 = nrmtab[s3];
            float4 a0 = h4[s0 * 8 + q];
            float4 a1 = h4[s1 * 8 + q];
            float4 a2 = h4[s2 * 8 + q];
            float4 a3 = h4[s3 * 8 + q];
            acc.x += (a0.x * w0 + a1.x * w1) + (a2.x * w2 + a3.x * w3);
            acc.y += (a0.y * w0 + a1.y * w1) + (a2.y * w2 + a3.y * w3);
            acc.z += (a0.z * w0 + a1.z * w1) + (a2.z * w2 + a3.z * w3);
            acc.w += (a0.w * w0 + a1.w * w1) + (a2.w * w2 + a3.w * w3);
        }
        for (; j < deg; ++j) {
            int s = esl[st + j];
            float w = nrmtab[s];
            float4 a = h4[s * 8 + q];
            acc.x += a.x * w; acc.y += a.y * w;
            acc.z += a.z * w; acc.w += a.w * w;
        }
        int node = (r << SB_SHIFT) + (half << 7) + l;
        if (node < N_NODES) {
            float nrm = rsqrtf((float)(deg > 1 ? deg : 1));
            float4 o = make_float4(acc.x * nrm + bb.x, acc.y * nrm + bb.y,
                                   acc.z * nrm + bb.z, acc.w * nrm + bb.w);
            reinterpret_cast<float4*>(out)[(size_t)node * 8 + q] = o;
        }
    }
}

// ---------------------------------------------------------------------------
extern "C" void kernel_launch(void* const* d_in, const int* in_sizes, int n_in,
                              void* d_out, int out_size, void* d_ws, size_t ws_size,
                              hipStream_t stream) {
    const float* x   = (const float*)d_in[0];
    const int*   src = (const int*)d_in[1];
    const int*   dst = (const int*)d_in[2];
    const float* W   = (const float*)d_in[3];
    const float* b   = (const float*)d_in[4];
    float* out = (float*)d_out;

    // ws: nrmtab f32[N] | qcnt u64[NSB] | pad | h f32[N*32] |
    //     gsb u32[NSB*SBCAP] | gss u8[NSB*SBCAP]
    float* nrmtab = (float*)d_ws;                                  // 400000 B
    unsigned long long* qcnt = (unsigned long long*)(nrmtab + N_NODES);
    int* qcnt2   = (int*)qcnt;
    float* h     = (float*)((char*)qcnt + NSB * 8 + 8);            // 16B aligned
    unsigned* gsb = (unsigned*)(h + (size_t)N_NODES * OUT_DIM);
    unsigned char* gss = (unsigned char*)(gsb + (size_t)NSB * SBCAP);

    hipMemsetAsync(qcnt, 0, NSB * sizeof(unsigned long long), stream);

    k_mega<<<NB1 + NGB, 512, 0, stream>>>(src, dst, qcnt, gsb, gss, x, W, h);

    k_deg2<<<NSB, 256, 0, stream>>>(qcnt2, gss, nrmtab);

    k_combo2<<<2 * NSB, 512, 0, stream>>>(qcnt2, gsb, h, nrmtab, b, out);
}